// Round 6
// baseline (517.217 us; speedup 1.0000x reference)
//
#include <hip/hip_runtime.h>
#include <math.h>

#define EPSF 1e-8f
#define MARGIN 4e-3f

constexpr int Bn = 16, Cc = 256, HW = 1024, Ee = 512, Vv = 8192;
constexpr int Mm = Bn * HW; // 16384 pixels

// d_out float offsets: z | z_q | decoder_input | tokens(float)
constexpr long O_Z   = 0;
constexpr long O_ZQ  = 8388608;
constexpr long O_DEC = 16777216;
constexpr long O_TOK = 25165824;

typedef __attribute__((ext_vector_type(8))) short s16x8;
typedef __attribute__((ext_vector_type(4))) short s16x4;
typedef __attribute__((ext_vector_type(8))) _Float16 f16x8;
typedef __attribute__((ext_vector_type(4))) float f32x4;

__device__ __forceinline__ unsigned short f2h(float x) {
    _Float16 h = (_Float16)x;
    return __builtin_bit_cast(unsigned short, h);
}
__device__ __forceinline__ float h2f(unsigned short b) {
    return (float)__builtin_bit_cast(_Float16, b);
}

// ---------------- small prep kernels ----------------

__global__ void k_wT(const float* __restrict__ w, float* __restrict__ wT) {
    int gid = blockIdx.x * 256 + threadIdx.x;      // 0..131071
    int c = gid >> 9, e = gid & 511;
    wT[gid] = w[e * Cc + c];                        // wT[c][e]
}

// fused: embedding norms + normalized fp16 B
__global__ void k_enB(const float* __restrict__ emb, float* __restrict__ en_inv,
                      float* __restrict__ en_norm, unsigned short* __restrict__ Bhi) {
    int v = blockIdx.x * 4 + (threadIdx.x >> 6);    // one wave per row
    int lane = threadIdx.x & 63;
    const float* row = emb + (long)v * Ee + lane * 8;
    float4 d0 = *(const float4*)row;
    float4 d1 = *(const float4*)(row + 4);
    float s = 0.f;
    s = fmaf(d0.x, d0.x, s); s = fmaf(d0.y, d0.y, s);
    s = fmaf(d0.z, d0.z, s); s = fmaf(d0.w, d0.w, s);
    s = fmaf(d1.x, d1.x, s); s = fmaf(d1.y, d1.y, s);
    s = fmaf(d1.z, d1.z, s); s = fmaf(d1.w, d1.w, s);
#pragma unroll
    for (int off = 32; off; off >>= 1) s += __shfl_xor(s, off);
    float n = sqrtf(s);
    float inv = 1.0f / (EPSF + n);
    if (lane == 0) { en_norm[v] = EPSF + n; en_inv[v] = inv; }
    s16x8 h;
    h[0] = (short)f2h(d0.x * inv); h[1] = (short)f2h(d0.y * inv);
    h[2] = (short)f2h(d0.z * inv); h[3] = (short)f2h(d0.w * inv);
    h[4] = (short)f2h(d1.x * inv); h[5] = (short)f2h(d1.y * inv);
    h[6] = (short)f2h(d1.z * inv); h[7] = (short)f2h(d1.w * inv);
    *(s16x8*)(Bhi + (long)v * Ee + lane * 8) = h;
}

// ---------------- GEMM1 (+ fused per-pixel sumsq partials) ----------------

__global__ __launch_bounds__(256) void k_gemm1(const float* __restrict__ x,
                                               const float* __restrict__ wT,
                                               const float* __restrict__ bias,
                                               float* __restrict__ z,
                                               float* __restrict__ sumsq_part) {
    __shared__ float As[32][64];
    __shared__ float Bs[32][64];
    int m0 = blockIdx.x * 64;                 // pixel tile
    int b = m0 >> 10, hw0 = m0 & 1023;
    int e0 = blockIdx.y * 64;
    int t = threadIdx.x;
    int mi = t >> 4, ni = t & 15;
    float acc[4][4] = {};
    for (int c0 = 0; c0 < Cc; c0 += 32) {
#pragma unroll
        for (int q = 0; q < 2; ++q) {
            int f = t + 256 * q;
            int kk = f >> 4, m4 = (f & 15) * 4;
            *(float4*)&As[kk][m4] = *(const float4*)(x + ((long)(b * Cc + c0 + kk)) * HW + hw0 + m4);
            *(float4*)&Bs[kk][m4] = *(const float4*)(wT + (long)(c0 + kk) * Ee + e0 + m4);
        }
        __syncthreads();
#pragma unroll
        for (int kk = 0; kk < 32; ++kk) {
            float4 a = *(float4*)&As[kk][mi * 4];
            float4 bv = *(float4*)&Bs[kk][ni * 4];
            float av[4] = {a.x, a.y, a.z, a.w};
            float bb[4] = {bv.x, bv.y, bv.z, bv.w};
#pragma unroll
            for (int r = 0; r < 4; ++r)
#pragma unroll
                for (int c = 0; c < 4; ++c) acc[r][c] = fmaf(av[r], bb[c], acc[r][c]);
        }
        __syncthreads();
    }
    float sq[4] = {0.f, 0.f, 0.f, 0.f};
#pragma unroll
    for (int c = 0; c < 4; ++c) {
        int e = e0 + ni * 4 + c;
        float be = bias[e];
        float4 o = make_float4(acc[0][c] + be, acc[1][c] + be, acc[2][c] + be, acc[3][c] + be);
        *(float4*)(z + ((long)(b * Ee + e)) * HW + hw0 + mi * 4) = o;
        sq[0] = fmaf(o.x, o.x, sq[0]); sq[1] = fmaf(o.y, o.y, sq[1]);
        sq[2] = fmaf(o.z, o.z, sq[2]); sq[3] = fmaf(o.w, o.w, sq[3]);
    }
#pragma unroll
    for (int r = 0; r < 4; ++r)
#pragma unroll
        for (int off = 1; off < 16; off <<= 1) sq[r] += __shfl_xor(sq[r], off);
    if (ni == 0) {
#pragma unroll
        for (int r = 0; r < 4; ++r)
            sumsq_part[(long)(m0 + mi * 4 + r) * 8 + blockIdx.y] = sq[r];
    }
}

// ---------------- A split: zn -> A_hi/A_lo fp16 (also finalizes inv_zn) ----------------

__global__ void k_Asplit(const float* __restrict__ z, const float* __restrict__ sumsq_part,
                         unsigned short* __restrict__ Ahi, unsigned short* __restrict__ Alo,
                         float* __restrict__ inv_zn) {
    __shared__ float tile[64][65];
    __shared__ float inv_s[64];
    int p0 = (blockIdx.x >> 3) * 64;   // 256 p-tiles
    int e0 = (blockIdx.x & 7) * 64;    // 8 e-tiles
    int b = p0 >> 10, hw0 = p0 & 1023;
    int t = threadIdx.x;
    if (t < 64) {
        const float* sp = sumsq_part + (long)(p0 + t) * 8;
        float s = ((sp[0] + sp[1]) + (sp[2] + sp[3])) + ((sp[4] + sp[5]) + (sp[6] + sp[7]));
        float inv = 1.0f / (EPSF + sqrtf(s));
        inv_s[t] = inv;
        if ((blockIdx.x & 7) == 0) inv_zn[p0 + t] = inv;
    }
#pragma unroll
    for (int q = 0; q < 4; ++q) {
        int f = t + 256 * q;
        int e_l = f >> 4, p4 = (f & 15) * 4;
        float4 d = *(const float4*)(z + ((long)(b * Ee + e0 + e_l)) * HW + hw0 + p4);
        tile[e_l][p4 + 0] = d.x; tile[e_l][p4 + 1] = d.y;
        tile[e_l][p4 + 2] = d.z; tile[e_l][p4 + 3] = d.w;
    }
    __syncthreads();
#pragma unroll
    for (int q = 0; q < 4; ++q) {
        int f = t + 256 * q;
        int p_l = f >> 4, e4 = (f & 15) * 4;
        float inv = inv_s[p_l];
        s16x4 h, lo;
#pragma unroll
        for (int j = 0; j < 4; ++j) {
            float xv = tile[e4 + j][p_l] * inv;
            unsigned short hh = f2h(xv);
            h[j]  = (short)hh;
            lo[j] = (short)f2h(xv - h2f(hh));
        }
        long off = (long)(p0 + p_l) * Ee + e0 + e4;
        *(s16x4*)(Ahi + off) = h;
        *(s16x4*)(Alo + off) = lo;
    }
}

// ---------------- single-pass fp16 MFMA sims GEMM + winner/extras epilogue ----------------
// 8192 blocks (128 m x 64 v), 256 thr = 4 waves (2x2), 128x128 tile, K=512.
// v3: global_load_lds (16B) double-buffered staging, ONE __syncthreads per
// K-step (its vmcnt(0) drains DMAs issued one full compute-phase earlier;
// stage-next is issued after the barrier, so the buffer it overwrites was
// last read two phases back -> race-free). Pre-swizzled global source with
// linear LDS dest; readers apply the same XOR (rule #21).

__global__ __launch_bounds__(256, 2) void k_sims(const unsigned short* __restrict__ Ahi,
                                                 const unsigned short* __restrict__ Bhi,
                                                 float* __restrict__ part_v,
                                                 int* __restrict__ part_i,
                                                 float2* __restrict__ extras,
                                                 int* __restrict__ cnt) {
    __shared__ short As[2][8192];   // [buf][row*64 + slot*8 + e]  16KB each
    __shared__ short Bs[2][8192];
    __shared__ float red_v[2][2][64];
    __shared__ int   red_i[2][2][64];
    __shared__ float red_m[2][64];
    __shared__ int   red_wi[2][64];

    int t = threadIdx.x;
    int wg = blockIdx.x;
    int xcd = wg & 7, r = wg >> 3;
    int bx = xcd * 16 + (r & 15);     // 0..127  (m-tile), XCD-chunked
    int by = r >> 4;                  // 0..63   (v-tile)
    long m0 = (long)bx * 128, n0 = (long)by * 128;

    int wid = t >> 6, l = t & 63;
    int wr = wid >> 1, wc = wid & 1;
    int l15 = l & 15, lg = l >> 4;

    // stage one 128x64 fp16 tile (1024 16B-slots) via 4 DMAs/thread
    auto stage = [&](const unsigned short* gbase, short* region, long row0, int k0) {
#pragma unroll
        for (int j = 0; j < 4; ++j) {
            int i = j * 256 + t;               // slot 0..1023
            int rr = i >> 3, s = i & 7;
            int sp = s ^ (rr & 7);             // pre-swizzled global source
            const unsigned short* gp = gbase + (row0 + rr) * Ee + k0 + sp * 8;
            short* lp = region + (long)(j * 256 + (t & ~63)) * 8;  // wave-uniform
            __builtin_amdgcn_global_load_lds(
                (const __attribute__((address_space(1))) unsigned int*)gp,
                (__attribute__((address_space(3))) unsigned int*)lp, 16, 0, 0);
        }
    };

    f32x4 acc[4][4];
#pragma unroll
    for (int i = 0; i < 4; ++i)
#pragma unroll
        for (int j = 0; j < 4; ++j) acc[i][j] = (f32x4){0.f, 0.f, 0.f, 0.f};

    stage(Ahi, &As[0][0], m0, 0);
    stage(Bhi, &Bs[0][0], n0, 0);

    for (int kt = 0; kt < 8; ++kt) {
        int cur = kt & 1;
        __syncthreads();   // vmcnt(0)+lgkmcnt(0)+barrier: cur DMAs landed for all
        if (kt < 7) {
            stage(Ahi, &As[cur ^ 1][0], m0, (kt + 1) * 64);
            stage(Bhi, &Bs[cur ^ 1][0], n0, (kt + 1) * 64);
        }
        s16x8 af[4][2], bf[4][2];
#pragma unroll
        for (int mt = 0; mt < 4; ++mt)
#pragma unroll
            for (int kk = 0; kk < 2; ++kk) {
                int row = wr * 64 + mt * 16 + l15;
                int g = kk * 4 + lg;
                af[mt][kk] = *(const s16x8*)&As[cur][row * 64 + ((g ^ (row & 7)) * 8)];
                int nrow = wc * 64 + mt * 16 + l15;
                bf[mt][kk] = *(const s16x8*)&Bs[cur][nrow * 64 + ((g ^ (nrow & 7)) * 8)];
            }
#pragma unroll
        for (int kk = 0; kk < 2; ++kk)
#pragma unroll
            for (int mt = 0; mt < 4; ++mt)
#pragma unroll
                for (int nt = 0; nt < 4; ++nt)
                    acc[mt][nt] = __builtin_amdgcn_mfma_f32_16x16x32_f16(
                        __builtin_bit_cast(f16x8, af[mt][kk]),
                        __builtin_bit_cast(f16x8, bf[nt][kk]), acc[mt][nt], 0, 0, 0);
    }

    // ---- winner epilogue (C/D: col = l&15, row = (l>>4)*4 + reg) ----
#pragma unroll
    for (int mt = 0; mt < 4; ++mt)
#pragma unroll
        for (int rg = 0; rg < 4; ++rg) {
            float best = -3e38f; int bi = 0x7FFFFFFF;
#pragma unroll
            for (int nt = 0; nt < 4; ++nt) {
                float val = acc[mt][nt][rg];
                int idx = (int)n0 + wc * 64 + nt * 16 + l15;
                if (val > best) { best = val; bi = idx; }
            }
#pragma unroll
            for (int off = 1; off < 16; off <<= 1) {
                float ov = __shfl_xor(best, off);
                int oi = __shfl_xor(bi, off);
                if (ov > best || (ov == best && oi < bi)) { best = ov; bi = oi; }
            }
            if (l15 == 0) {
                int rloc = mt * 16 + lg * 4 + rg;
                red_v[wr][wc][rloc] = best;
                red_i[wr][wc][rloc] = bi;
            }
        }
    __syncthreads();
    if (t < 128) {
        int wr_ = t >> 6, rloc = t & 63;
        float va = red_v[wr_][0][rloc]; int ia = red_i[wr_][0][rloc];
        float vb = red_v[wr_][1][rloc]; int ib = red_i[wr_][1][rloc];
        if (vb > va || (vb == va && ib < ia)) { va = vb; ia = ib; }
        long m = m0 + wr_ * 64 + rloc;
        part_v[m * 64 + by] = va;
        part_i[m * 64 + by] = ia;
        red_m[wr_][rloc] = va;
        red_wi[wr_][rloc] = ia;
    }
    __syncthreads();
    // ---- extras: every non-winner col within MARGIN of the stripe max ----
#pragma unroll
    for (int mt = 0; mt < 4; ++mt)
#pragma unroll
        for (int rg = 0; rg < 4; ++rg) {
            int rloc = mt * 16 + lg * 4 + rg;
            float bm = red_m[wr][rloc];
            int wi_ = red_wi[wr][rloc];
            long p = m0 + wr * 64 + rloc;
            float thr = bm - MARGIN;
#pragma unroll
            for (int nt = 0; nt < 4; ++nt) {
                float val = acc[mt][nt][rg];
                int idx = (int)n0 + wc * 64 + nt * 16 + l15;
                if (val >= thr && idx != wi_) {
                    int slot = atomicAdd(&cnt[p], 1);
                    if (slot < 64) extras[p * 64 + slot] = make_float2(val, __int_as_float(idx));
                }
            }
        }
}

// ---------------- k_pick: per-pixel global m1, candidate set, exact f32 rescore ----------------

__global__ __launch_bounds__(256) void k_pick(const float* __restrict__ part_v,
                                              const int* __restrict__ part_i,
                                              const float2* __restrict__ extras,
                                              const int* __restrict__ cnt,
                                              const unsigned short* __restrict__ Ahi,
                                              const unsigned short* __restrict__ Alo,
                                              const float* __restrict__ emb,
                                              const float* __restrict__ en_inv,
                                              int* __restrict__ tok_i,
                                              float* __restrict__ tok_f) {
    int p = blockIdx.x * 4 + (threadIdx.x >> 6);
    int lane = threadIdx.x & 63;
    float wv = part_v[(long)p * 64 + lane];
    int wi = part_i[(long)p * 64 + lane];
    // global fp16 max over the 64 stripe winners
    float m1 = wv;
#pragma unroll
    for (int off = 1; off < 64; off <<= 1) {
        float ov = __shfl_xor(m1, off);
        if (ov > m1) m1 = ov;
    }
    float thr = m1 - MARGIN;
    int n = cnt[p]; if (n > 64) n = 64;
    float ev = -3e38f; int ei = 0;
    if (lane < n) {
        float2 e2 = extras[(long)p * 64 + lane];
        ev = e2.x; ei = __float_as_int(e2.y);
    }
    unsigned long long mw = __ballot(wv >= thr);
    unsigned long long me = __ballot(ev >= thr);
    // preload this pixel's zn row slice (reconstructed f32)
    s16x8 ah = *(const s16x8*)(Ahi + (long)p * Ee + lane * 8);
    s16x8 al = *(const s16x8*)(Alo + (long)p * Ee + lane * 8);
    float a[8];
#pragma unroll
    for (int j = 0; j < 8; ++j)
        a[j] = h2f((unsigned short)ah[j]) + h2f((unsigned short)al[j]);

    float best = -3e38f; int bi = 0x7FFFFFFF;
    auto rescore = [&](int v) {
        const float* er = emb + (long)v * Ee + lane * 8;
        float4 b0 = *(const float4*)er;
        float4 b1 = *(const float4*)(er + 4);
        float s = 0.f;
        s = fmaf(a[0], b0.x, s); s = fmaf(a[1], b0.y, s);
        s = fmaf(a[2], b0.z, s); s = fmaf(a[3], b0.w, s);
        s = fmaf(a[4], b1.x, s); s = fmaf(a[5], b1.y, s);
        s = fmaf(a[6], b1.z, s); s = fmaf(a[7], b1.w, s);
#pragma unroll
        for (int off = 1; off < 64; off <<= 1) s += __shfl_xor(s, off);
        s *= en_inv[v];
        if (s > best || (s == best && v < bi)) { best = s; bi = v; }
    };
    while (mw) {
        int b = __ffsll(mw) - 1; mw &= mw - 1;
        rescore(__shfl(wi, b));
    }
    while (me) {
        int b = __ffsll(me) - 1; me &= me - 1;
        rescore(__shfl(ei, b));
    }
    if (lane == 0) { tok_i[p] = bi; tok_f[p] = (float)bi; }
}

// ---------------- finalize: z_q gather + straight-through blend ----------------

__global__ void k_final(const float* __restrict__ z, const float* __restrict__ emb,
                        const int* __restrict__ tok, const float* __restrict__ inv_zn,
                        const float* __restrict__ en_inv, const float* __restrict__ en_norm,
                        float* __restrict__ zq, float* __restrict__ dec) {
    long gid = (long)blockIdx.x * 256 + threadIdx.x;   // 0..8388607
    int hw = (int)(gid & 1023);
    int b  = (int)(gid >> 19);
    int p  = (b << 10) | hw;
    int e  = (int)((gid >> 10) & 511);
    int tk = tok[p];
    float zqv = emb[(long)tk * Ee + e];
    float nq  = en_norm[tk];
    float nzq = zqv * en_inv[tk];
    float zv  = z[gid];
    float nz  = zv * inv_zn[p];
    zq[gid]  = zqv;
    dec[gid] = (nz + (nzq - nz)) * nq;
}

// ---------------- launch ----------------

extern "C" void kernel_launch(void* const* d_in, const int* in_sizes, int n_in,
                              void* d_out, int out_size, void* d_ws, size_t ws_size,
                              hipStream_t stream) {
    const float* x     = (const float*)d_in[0];
    const float* w_pre = (const float*)d_in[1];
    const float* b_pre = (const float*)d_in[2];
    const float* emb   = (const float*)d_in[3];

    float* out  = (float*)d_out;
    float* z    = out + O_Z;
    float* zq   = out + O_ZQ;
    float* dec  = out + O_DEC;
    float* tokf = out + O_TOK;

    // zq region (32MB): Ahi | Alo  fp16 [16384][512] each (dead until k_final)
    unsigned short* Ahi = (unsigned short*)zq;
    unsigned short* Alo = Ahi + (long)Mm * Ee;
    // dec region (8M floats): Bhi(2M) | part_v(1M) | part_i(1M) | extras(2M) | cnt | sumsq
    unsigned short* Bhi = (unsigned short*)dec;
    float*  part_v = dec + 2 * 1024 * 1024;
    int*    part_i = (int*)(dec + 3 * 1024 * 1024);
    float2* extras = (float2*)(dec + 4 * 1024 * 1024);
    int*    cnt    = (int*)(dec + 6 * 1024 * 1024);
    float*  sumsq_part = dec + 6 * 1024 * 1024 + 32768;   // 16384*8 floats

    float* ws      = (float*)d_ws;
    float* wT      = ws;                // 131072
    float* en_inv  = wT + 131072;       // 8192
    float* en_norm = en_inv + 8192;     // 8192
    float* inv_zn  = en_norm + 8192;    // 16384
    int*   tok_i   = (int*)(inv_zn + 16384); // 16384

    k_wT<<<512, 256, 0, stream>>>(w_pre, wT);
    k_enB<<<2048, 256, 0, stream>>>(emb, en_inv, en_norm, Bhi);
    dim3 g1(Mm / 64, Ee / 64);
    k_gemm1<<<g1, 256, 0, stream>>>(x, wT, b_pre, z, sumsq_part);
    k_Asplit<<<2048, 256, 0, stream>>>(z, sumsq_part, Ahi, Alo, inv_zn);
    hipMemsetAsync((void*)cnt, 0, Mm * sizeof(int), stream);
    k_sims<<<8192, 256, 0, stream>>>(Ahi, Bhi, part_v, part_i, extras, cnt);
    k_pick<<<Mm / 4, 256, 0, stream>>>(part_v, part_i, extras, cnt, Ahi, Alo, emb,
                                       en_inv, tok_i, tokf);
    k_final<<<(int)(8388608 / 256), 256, 0, stream>>>(z, emb, tok_i, inv_zn, en_inv, en_norm, zq, dec);
}

// Round 7
// 426.155 us; speedup vs baseline: 1.2137x; 1.2137x over previous
//
#include <hip/hip_runtime.h>
#include <math.h>

#define EPSF 1e-8f
#define MARGIN 4e-3f

constexpr int Bn = 16, Cc = 256, HW = 1024, Ee = 512, Vv = 8192;
constexpr int Mm = Bn * HW; // 16384 pixels

// d_out float offsets: z | z_q | decoder_input | tokens(float)
constexpr long O_Z   = 0;
constexpr long O_ZQ  = 8388608;
constexpr long O_DEC = 16777216;
constexpr long O_TOK = 25165824;

typedef __attribute__((ext_vector_type(8))) short s16x8;
typedef __attribute__((ext_vector_type(4))) short s16x4;
typedef __attribute__((ext_vector_type(8))) _Float16 f16x8;
typedef __attribute__((ext_vector_type(4))) float f32x4;

__device__ __forceinline__ unsigned short f2h(float x) {
    _Float16 h = (_Float16)x;
    return __builtin_bit_cast(unsigned short, h);
}
__device__ __forceinline__ float h2f(unsigned short b) {
    return (float)__builtin_bit_cast(_Float16, b);
}

// ---------------- small prep kernels ----------------

__global__ void k_wT(const float* __restrict__ w, float* __restrict__ wT) {
    int gid = blockIdx.x * 256 + threadIdx.x;      // 0..131071
    int c = gid >> 9, e = gid & 511;
    wT[gid] = w[e * Cc + c];                        // wT[c][e]
}

// fused: embedding norms + normalized fp16 B
__global__ void k_enB(const float* __restrict__ emb, float* __restrict__ en_inv,
                      float* __restrict__ en_norm, unsigned short* __restrict__ Bhi) {
    int v = blockIdx.x * 4 + (threadIdx.x >> 6);    // one wave per row
    int lane = threadIdx.x & 63;
    const float* row = emb + (long)v * Ee + lane * 8;
    float4 d0 = *(const float4*)row;
    float4 d1 = *(const float4*)(row + 4);
    float s = 0.f;
    s = fmaf(d0.x, d0.x, s); s = fmaf(d0.y, d0.y, s);
    s = fmaf(d0.z, d0.z, s); s = fmaf(d0.w, d0.w, s);
    s = fmaf(d1.x, d1.x, s); s = fmaf(d1.y, d1.y, s);
    s = fmaf(d1.z, d1.z, s); s = fmaf(d1.w, d1.w, s);
#pragma unroll
    for (int off = 32; off; off >>= 1) s += __shfl_xor(s, off);
    float n = sqrtf(s);
    float inv = 1.0f / (EPSF + n);
    if (lane == 0) { en_norm[v] = EPSF + n; en_inv[v] = inv; }
    s16x8 h;
    h[0] = (short)f2h(d0.x * inv); h[1] = (short)f2h(d0.y * inv);
    h[2] = (short)f2h(d0.z * inv); h[3] = (short)f2h(d0.w * inv);
    h[4] = (short)f2h(d1.x * inv); h[5] = (short)f2h(d1.y * inv);
    h[6] = (short)f2h(d1.z * inv); h[7] = (short)f2h(d1.w * inv);
    *(s16x8*)(Bhi + (long)v * Ee + lane * 8) = h;
}

// ---------------- GEMM1 (+ fused per-pixel sumsq partials) ----------------

__global__ __launch_bounds__(256) void k_gemm1(const float* __restrict__ x,
                                               const float* __restrict__ wT,
                                               const float* __restrict__ bias,
                                               float* __restrict__ z,
                                               float* __restrict__ sumsq_part) {
    __shared__ float As[32][64];
    __shared__ float Bs[32][64];
    int m0 = blockIdx.x * 64;                 // pixel tile
    int b = m0 >> 10, hw0 = m0 & 1023;
    int e0 = blockIdx.y * 64;
    int t = threadIdx.x;
    int mi = t >> 4, ni = t & 15;
    float acc[4][4] = {};
    for (int c0 = 0; c0 < Cc; c0 += 32) {
#pragma unroll
        for (int q = 0; q < 2; ++q) {
            int f = t + 256 * q;
            int kk = f >> 4, m4 = (f & 15) * 4;
            *(float4*)&As[kk][m4] = *(const float4*)(x + ((long)(b * Cc + c0 + kk)) * HW + hw0 + m4);
            *(float4*)&Bs[kk][m4] = *(const float4*)(wT + (long)(c0 + kk) * Ee + e0 + m4);
        }
        __syncthreads();
#pragma unroll
        for (int kk = 0; kk < 32; ++kk) {
            float4 a = *(float4*)&As[kk][mi * 4];
            float4 bv = *(float4*)&Bs[kk][ni * 4];
            float av[4] = {a.x, a.y, a.z, a.w};
            float bb[4] = {bv.x, bv.y, bv.z, bv.w};
#pragma unroll
            for (int r = 0; r < 4; ++r)
#pragma unroll
                for (int c = 0; c < 4; ++c) acc[r][c] = fmaf(av[r], bb[c], acc[r][c]);
        }
        __syncthreads();
    }
    float sq[4] = {0.f, 0.f, 0.f, 0.f};
#pragma unroll
    for (int c = 0; c < 4; ++c) {
        int e = e0 + ni * 4 + c;
        float be = bias[e];
        float4 o = make_float4(acc[0][c] + be, acc[1][c] + be, acc[2][c] + be, acc[3][c] + be);
        *(float4*)(z + ((long)(b * Ee + e)) * HW + hw0 + mi * 4) = o;
        sq[0] = fmaf(o.x, o.x, sq[0]); sq[1] = fmaf(o.y, o.y, sq[1]);
        sq[2] = fmaf(o.z, o.z, sq[2]); sq[3] = fmaf(o.w, o.w, sq[3]);
    }
#pragma unroll
    for (int r = 0; r < 4; ++r)
#pragma unroll
        for (int off = 1; off < 16; off <<= 1) sq[r] += __shfl_xor(sq[r], off);
    if (ni == 0) {
#pragma unroll
        for (int r = 0; r < 4; ++r)
            sumsq_part[(long)(m0 + mi * 4 + r) * 8 + blockIdx.y] = sq[r];
    }
}

// ---------------- A split: zn -> A_hi/A_lo fp16 (also finalizes inv_zn) ----------------

__global__ void k_Asplit(const float* __restrict__ z, const float* __restrict__ sumsq_part,
                         unsigned short* __restrict__ Ahi, unsigned short* __restrict__ Alo,
                         float* __restrict__ inv_zn) {
    __shared__ float tile[64][65];
    __shared__ float inv_s[64];
    int p0 = (blockIdx.x >> 3) * 64;   // 256 p-tiles
    int e0 = (blockIdx.x & 7) * 64;    // 8 e-tiles
    int b = p0 >> 10, hw0 = p0 & 1023;
    int t = threadIdx.x;
    if (t < 64) {
        const float* sp = sumsq_part + (long)(p0 + t) * 8;
        float s = ((sp[0] + sp[1]) + (sp[2] + sp[3])) + ((sp[4] + sp[5]) + (sp[6] + sp[7]));
        float inv = 1.0f / (EPSF + sqrtf(s));
        inv_s[t] = inv;
        if ((blockIdx.x & 7) == 0) inv_zn[p0 + t] = inv;
    }
#pragma unroll
    for (int q = 0; q < 4; ++q) {
        int f = t + 256 * q;
        int e_l = f >> 4, p4 = (f & 15) * 4;
        float4 d = *(const float4*)(z + ((long)(b * Ee + e0 + e_l)) * HW + hw0 + p4);
        tile[e_l][p4 + 0] = d.x; tile[e_l][p4 + 1] = d.y;
        tile[e_l][p4 + 2] = d.z; tile[e_l][p4 + 3] = d.w;
    }
    __syncthreads();
#pragma unroll
    for (int q = 0; q < 4; ++q) {
        int f = t + 256 * q;
        int p_l = f >> 4, e4 = (f & 15) * 4;
        float inv = inv_s[p_l];
        s16x4 h, lo;
#pragma unroll
        for (int j = 0; j < 4; ++j) {
            float xv = tile[e4 + j][p_l] * inv;
            unsigned short hh = f2h(xv);
            h[j]  = (short)hh;
            lo[j] = (short)f2h(xv - h2f(hh));
        }
        long off = (long)(p0 + p_l) * Ee + e0 + e4;
        *(s16x4*)(Ahi + off) = h;
        *(s16x4*)(Alo + off) = lo;
    }
}

// ---------------- single-pass fp16 MFMA sims GEMM + winner/extras epilogue ----------------
// 8192 blocks (128 m x 64 v), 256 thr = 4 waves (2x2), 128x128 tile, K=512.
// v4 = m97 structure: SINGLE 32KB LDS buffer, global_load_lds(16B) staging,
// 2 barriers/K-step: {bar(drain DMA) -> ds_read frags -> bar(reads done) ->
// issue next DMAs -> MFMA}. DMAs overlap the MFMA cluster and the other 3
// resident blocks/CU (36KB LDS -> 4 blocks/CU). Pre-swizzled global source,
// linear LDS dest, XOR on read (rule #21; verified numerically R6).

__global__ __launch_bounds__(256, 4) void k_sims(const unsigned short* __restrict__ Ahi,
                                                 const unsigned short* __restrict__ Bhi,
                                                 float* __restrict__ part_v,
                                                 int* __restrict__ part_i,
                                                 float2* __restrict__ extras,
                                                 int* __restrict__ cnt) {
    __shared__ short As[8192];   // [row*64 + slot*8 + e]  16KB
    __shared__ short Bs[8192];
    __shared__ float red_v[2][2][64];
    __shared__ int   red_i[2][2][64];
    __shared__ float red_m[2][64];
    __shared__ int   red_wi[2][64];

    int t = threadIdx.x;
    int wg = blockIdx.x;
    int xcd = wg & 7, r = wg >> 3;
    int bx = xcd * 16 + (r & 15);     // 0..127  (m-tile), XCD-chunked
    int by = r >> 4;                  // 0..63   (v-tile)
    long m0 = (long)bx * 128, n0 = (long)by * 128;

    int wid = t >> 6, l = t & 63;
    int wr = wid >> 1, wc = wid & 1;
    int l15 = l & 15, lg = l >> 4;

    // stage one 128x64 fp16 tile (1024 16B-slots) via 4 DMAs/thread
    auto stage = [&](const unsigned short* gbase, short* region, long row0, int k0) {
#pragma unroll
        for (int j = 0; j < 4; ++j) {
            int i = j * 256 + t;               // slot 0..1023
            int rr = i >> 3, s = i & 7;
            int sp = s ^ (rr & 7);             // pre-swizzled global source
            const unsigned short* gp = gbase + (row0 + rr) * Ee + k0 + sp * 8;
            short* lp = region + (long)(j * 256 + (t & ~63)) * 8;  // wave-uniform
            __builtin_amdgcn_global_load_lds(
                (const __attribute__((address_space(1))) unsigned int*)gp,
                (__attribute__((address_space(3))) unsigned int*)lp, 16, 0, 0);
        }
    };

    f32x4 acc[4][4];
#pragma unroll
    for (int i = 0; i < 4; ++i)
#pragma unroll
        for (int j = 0; j < 4; ++j) acc[i][j] = (f32x4){0.f, 0.f, 0.f, 0.f};

    stage(Ahi, As, m0, 0);
    stage(Bhi, Bs, n0, 0);

    for (int kt = 0; kt < 8; ++kt) {
        __syncthreads();   // vmcnt(0)+barrier: tile kt landed for all waves
        s16x8 af[4][2], bf[4][2];
#pragma unroll
        for (int mt = 0; mt < 4; ++mt)
#pragma unroll
            for (int kk = 0; kk < 2; ++kk) {
                int row = wr * 64 + mt * 16 + l15;
                int g = kk * 4 + lg;
                af[mt][kk] = *(const s16x8*)&As[row * 64 + ((g ^ (row & 7)) * 8)];
                int nrow = wc * 64 + mt * 16 + l15;
                bf[mt][kk] = *(const s16x8*)&Bs[nrow * 64 + ((g ^ (nrow & 7)) * 8)];
            }
        __syncthreads();   // lgkmcnt(0)+barrier: all waves' reads complete
        if (kt < 7) {
            stage(Ahi, As, m0, (kt + 1) * 64);   // DMAs fly under the MFMAs
            stage(Bhi, Bs, n0, (kt + 1) * 64);
        }
#pragma unroll
        for (int kk = 0; kk < 2; ++kk)
#pragma unroll
            for (int mt = 0; mt < 4; ++mt)
#pragma unroll
                for (int nt = 0; nt < 4; ++nt)
                    acc[mt][nt] = __builtin_amdgcn_mfma_f32_16x16x32_f16(
                        __builtin_bit_cast(f16x8, af[mt][kk]),
                        __builtin_bit_cast(f16x8, bf[nt][kk]), acc[mt][nt], 0, 0, 0);
    }

    // ---- winner epilogue (C/D: col = l&15, row = (l>>4)*4 + reg) ----
#pragma unroll
    for (int mt = 0; mt < 4; ++mt)
#pragma unroll
        for (int rg = 0; rg < 4; ++rg) {
            float best = -3e38f; int bi = 0x7FFFFFFF;
#pragma unroll
            for (int nt = 0; nt < 4; ++nt) {
                float val = acc[mt][nt][rg];
                int idx = (int)n0 + wc * 64 + nt * 16 + l15;
                if (val > best) { best = val; bi = idx; }
            }
#pragma unroll
            for (int off = 1; off < 16; off <<= 1) {
                float ov = __shfl_xor(best, off);
                int oi = __shfl_xor(bi, off);
                if (ov > best || (ov == best && oi < bi)) { best = ov; bi = oi; }
            }
            if (l15 == 0) {
                int rloc = mt * 16 + lg * 4 + rg;
                red_v[wr][wc][rloc] = best;
                red_i[wr][wc][rloc] = bi;
            }
        }
    __syncthreads();
    if (t < 128) {
        int wr_ = t >> 6, rloc = t & 63;
        float va = red_v[wr_][0][rloc]; int ia = red_i[wr_][0][rloc];
        float vb = red_v[wr_][1][rloc]; int ib = red_i[wr_][1][rloc];
        if (vb > va || (vb == va && ib < ia)) { va = vb; ia = ib; }
        long m = m0 + wr_ * 64 + rloc;
        part_v[m * 64 + by] = va;
        part_i[m * 64 + by] = ia;
        red_m[wr_][rloc] = va;
        red_wi[wr_][rloc] = ia;
    }
    __syncthreads();
    // ---- extras: every non-winner col within MARGIN of the stripe max ----
#pragma unroll
    for (int mt = 0; mt < 4; ++mt)
#pragma unroll
        for (int rg = 0; rg < 4; ++rg) {
            int rloc = mt * 16 + lg * 4 + rg;
            float bm = red_m[wr][rloc];
            int wi_ = red_wi[wr][rloc];
            long p = m0 + wr * 64 + rloc;
            float thr = bm - MARGIN;
#pragma unroll
            for (int nt = 0; nt < 4; ++nt) {
                float val = acc[mt][nt][rg];
                int idx = (int)n0 + wc * 64 + nt * 16 + l15;
                if (val >= thr && idx != wi_) {
                    int slot = atomicAdd(&cnt[p], 1);
                    if (slot < 64) extras[p * 64 + slot] = make_float2(val, __int_as_float(idx));
                }
            }
        }
}

// ---------------- k_pick: per-pixel global m1, candidate set, exact f32 rescore ----------------

__global__ __launch_bounds__(256) void k_pick(const float* __restrict__ part_v,
                                              const int* __restrict__ part_i,
                                              const float2* __restrict__ extras,
                                              const int* __restrict__ cnt,
                                              const unsigned short* __restrict__ Ahi,
                                              const unsigned short* __restrict__ Alo,
                                              const float* __restrict__ emb,
                                              const float* __restrict__ en_inv,
                                              int* __restrict__ tok_i,
                                              float* __restrict__ tok_f) {
    int p = blockIdx.x * 4 + (threadIdx.x >> 6);
    int lane = threadIdx.x & 63;
    float wv = part_v[(long)p * 64 + lane];
    int wi = part_i[(long)p * 64 + lane];
    // global fp16 max over the 64 stripe winners
    float m1 = wv;
#pragma unroll
    for (int off = 1; off < 64; off <<= 1) {
        float ov = __shfl_xor(m1, off);
        if (ov > m1) m1 = ov;
    }
    float thr = m1 - MARGIN;
    int n = cnt[p]; if (n > 64) n = 64;
    float ev = -3e38f; int ei = 0;
    if (lane < n) {
        float2 e2 = extras[(long)p * 64 + lane];
        ev = e2.x; ei = __float_as_int(e2.y);
    }
    unsigned long long mw = __ballot(wv >= thr);
    unsigned long long me = __ballot(ev >= thr);
    // preload this pixel's zn row slice (reconstructed f32)
    s16x8 ah = *(const s16x8*)(Ahi + (long)p * Ee + lane * 8);
    s16x8 al = *(const s16x8*)(Alo + (long)p * Ee + lane * 8);
    float a[8];
#pragma unroll
    for (int j = 0; j < 8; ++j)
        a[j] = h2f((unsigned short)ah[j]) + h2f((unsigned short)al[j]);

    float best = -3e38f; int bi = 0x7FFFFFFF;
    auto rescore = [&](int v) {
        const float* er = emb + (long)v * Ee + lane * 8;
        float4 b0 = *(const float4*)er;
        float4 b1 = *(const float4*)(er + 4);
        float s = 0.f;
        s = fmaf(a[0], b0.x, s); s = fmaf(a[1], b0.y, s);
        s = fmaf(a[2], b0.z, s); s = fmaf(a[3], b0.w, s);
        s = fmaf(a[4], b1.x, s); s = fmaf(a[5], b1.y, s);
        s = fmaf(a[6], b1.z, s); s = fmaf(a[7], b1.w, s);
#pragma unroll
        for (int off = 1; off < 64; off <<= 1) s += __shfl_xor(s, off);
        s *= en_inv[v];
        if (s > best || (s == best && v < bi)) { best = s; bi = v; }
    };
    while (mw) {
        int b = __ffsll(mw) - 1; mw &= mw - 1;
        rescore(__shfl(wi, b));
    }
    while (me) {
        int b = __ffsll(me) - 1; me &= me - 1;
        rescore(__shfl(ei, b));
    }
    if (lane == 0) { tok_i[p] = bi; tok_f[p] = (float)bi; }
}

// ---------------- finalize: z_q gather + straight-through blend ----------------

__global__ void k_final(const float* __restrict__ z, const float* __restrict__ emb,
                        const int* __restrict__ tok, const float* __restrict__ inv_zn,
                        const float* __restrict__ en_inv, const float* __restrict__ en_norm,
                        float* __restrict__ zq, float* __restrict__ dec) {
    long gid = (long)blockIdx.x * 256 + threadIdx.x;   // 0..8388607
    int hw = (int)(gid & 1023);
    int b  = (int)(gid >> 19);
    int p  = (b << 10) | hw;
    int e  = (int)((gid >> 10) & 511);
    int tk = tok[p];
    float zqv = emb[(long)tk * Ee + e];
    float nq  = en_norm[tk];
    float nzq = zqv * en_inv[tk];
    float zv  = z[gid];
    float nz  = zv * inv_zn[p];
    zq[gid]  = zqv;
    dec[gid] = (nz + (nzq - nz)) * nq;
}

// ---------------- launch ----------------

extern "C" void kernel_launch(void* const* d_in, const int* in_sizes, int n_in,
                              void* d_out, int out_size, void* d_ws, size_t ws_size,
                              hipStream_t stream) {
    const float* x     = (const float*)d_in[0];
    const float* w_pre = (const float*)d_in[1];
    const float* b_pre = (const float*)d_in[2];
    const float* emb   = (const float*)d_in[3];

    float* out  = (float*)d_out;
    float* z    = out + O_Z;
    float* zq   = out + O_ZQ;
    float* dec  = out + O_DEC;
    float* tokf = out + O_TOK;

    // zq region (32MB): Ahi | Alo  fp16 [16384][512] each (dead until k_final)
    unsigned short* Ahi = (unsigned short*)zq;
    unsigned short* Alo = Ahi + (long)Mm * Ee;
    // dec region (8M floats): Bhi(2M) | part_v(1M) | part_i(1M) | extras(2M) | cnt | sumsq
    unsigned short* Bhi = (unsigned short*)dec;
    float*  part_v = dec + 2 * 1024 * 1024;
    int*    part_i = (int*)(dec + 3 * 1024 * 1024);
    float2* extras = (float2*)(dec + 4 * 1024 * 1024);
    int*    cnt    = (int*)(dec + 6 * 1024 * 1024);
    float*  sumsq_part = dec + 6 * 1024 * 1024 + 32768;   // 16384*8 floats

    float* ws      = (float*)d_ws;
    float* wT      = ws;                // 131072
    float* en_inv  = wT + 131072;       // 8192
    float* en_norm = en_inv + 8192;     // 8192
    float* inv_zn  = en_norm + 8192;    // 16384
    int*   tok_i   = (int*)(inv_zn + 16384); // 16384

    k_wT<<<512, 256, 0, stream>>>(w_pre, wT);
    k_enB<<<2048, 256, 0, stream>>>(emb, en_inv, en_norm, Bhi);
    dim3 g1(Mm / 64, Ee / 64);
    k_gemm1<<<g1, 256, 0, stream>>>(x, wT, b_pre, z, sumsq_part);
    k_Asplit<<<2048, 256, 0, stream>>>(z, sumsq_part, Ahi, Alo, inv_zn);
    hipMemsetAsync((void*)cnt, 0, Mm * sizeof(int), stream);
    k_sims<<<8192, 256, 0, stream>>>(Ahi, Bhi, part_v, part_i, extras, cnt);
    k_pick<<<Mm / 4, 256, 0, stream>>>(part_v, part_i, extras, cnt, Ahi, Alo, emb,
                                       en_inv, tok_i, tokf);
    k_final<<<(int)(8388608 / 256), 256, 0, stream>>>(z, emb, tok_i, inv_zn, en_inv, en_norm, zq, dec);
}